// Round 15
// baseline (60.797 us; speedup 1.0000x reference)
//
#include <hip/hip_runtime.h>
#include <hip/hip_bf16.h>

// SPP patch extraction, fused single-launch, persistent + software-pipelined.
// feat (512,48,48) fp32; scales {4,6,8,10,12,14,16}, stride-2 SxS windows,
// adaptive max pool 7x7 -> (ny*nx, 512*49) per scale, concatenated.
//
// R15 = R10's unit structure (unit = (8-ch chunk, iy); P2 y-binned rp ->
// wave-autonomous emit with owb float4 staging) made PERSISTENT and
// PIPELINED: per unit, each wave (A) issues the NEXT unit's P2 global loads
// into registers, (B) emits the CURRENT unit from rp (stores stream while
// A's loads are in flight), then barrier, (C) reduces regs + ds_writes rp,
// barrier. This removes the per-round store-idle bubble where phase-locked
// blocks all sat in latency-bound P2 with zero stores in flight.
// One scale per block (2-template instantiation); block count per scale
// proportional to its output bytes (ny^2), total 1024 = 4 blocks/CU.

#define HW 48
#define CSTR (HW * HW)   // 2304
#define POOL 7
#define PE 25088         // 512*49 elems per patch
#define CH 8             // channels per block
#define RPS 50           // rp row stride (floats)

constexpr int cdiv7(int x) { return (x + 6) / 7; }
constexpr int nyf(int S) { return (HW - S) / 2 + 1; }
constexpr int max_bin(int S) {
    int m = 0;
    for (int i = 0; i < POOL; ++i) {
        int a = (i * S) / POOL, b = cdiv7((i + 1) * S);
        if (b - a > m) m = b - a;
    }
    return m;
}

template <int S>
__device__ __forceinline__ void run_segment(int sb, int nsb,
                                            const float* __restrict__ feat,
                                            float* __restrict__ outp,
                                            float* rp, float* owb) {
    constexpr int NY = nyf(S);
    constexpr int NU = 64 * NY;      // units in this scale segment
    constexpr int MB = max_bin(S);
    const int tid = threadIdx.x;
    const int wv = tid >> 6;
    const int lane = tid & 63;

    // register-staged P2: per wave 336 float2 items (56 rows x 24 cols / 4)
    float2 ld[6][MB];
    int dsaddr[6];

    auto stageA = [&](int u) {       // issue loads only (latency overlapped)
        const int iy = u >> 6;
        const int c0 = (u & 63) * CH;
        const float* fb = feat + (size_t)c0 * CSTR + (iy * 2) * HW;
#pragma unroll
        for (int j = 0; j < 6; ++j) {
            int k = lane + 64 * j;
            if (j < 5 || k < 336) {
                int t = wv * 336 + k;
                int c = t / 168;
                int rem = t - c * 168;
                int py = rem / 24;
                int xl = rem - py * 24;
                int ay = (py * S) / POOL;
                int szy = cdiv7((py + 1) * S) - ay;
                const float* wb = fb + c * CSTR + ay * HW + 2 * xl;
#pragma unroll
                for (int r = 0; r < MB; ++r)
                    ld[j][r] = *(const float2*)(wb + min(r, szy - 1) * HW);
                dsaddr[j] = (c * POOL + py) * RPS + 2 * xl;
            }
        }
    };

    auto reduceWrite = [&]() {       // consume regs -> rp
#pragma unroll
        for (int j = 0; j < 6; ++j) {
            int k = lane + 64 * j;
            if (j < 5 || k < 336) {
                float2 m = ld[j][0];
#pragma unroll
                for (int r = 1; r < MB; ++r) {
                    m.x = fmaxf(m.x, ld[j][r].x);
                    m.y = fmaxf(m.y, ld[j][r].y);
                }
                *(float2*)(rp + dsaddr[j]) = m;
            }
        }
    };

    auto emit = [&](int u) {         // R10's proven wave-autonomous emit
        const int iy = u >> 6;
        const int c0 = (u & 63) * CH;
        float* myout = owb + wv * 392;
        float* obase = outp + (size_t)iy * NY * PE + (size_t)c0 * 49;
        for (int ix = wv; ix < NY; ix += 4) {
            if (lane < 56) {
                const float* v = rp + lane * RPS + 2 * ix;   // 8B-aligned
                float x[S];
#pragma unroll
                for (int k = 0; k < S / 2; ++k) {
                    float2 p = *(const float2*)(v + 2 * k);
                    x[2 * k] = p.x;
                    x[2 * k + 1] = p.y;
                }
                float* ob = myout + lane * 7;
#pragma unroll
                for (int px = 0; px < POOL; ++px) {
                    int ax = (px * S) / POOL;                // compile-time
                    int bx = cdiv7((px + 1) * S);
                    float m = x[ax];
#pragma unroll
                    for (int k = ax + 1; k < bx; ++k) m = fmaxf(m, x[k]);
                    ob[px] = m;
                }
            }
            asm volatile("" ::: "memory");
            float* od = obase + (size_t)ix * PE;
            float4 vv = *(const float4*)(myout + 4 * lane);
            *(float4*)(od + 4 * lane) = vv;
            int k2 = lane + 64;
            if (k2 < 98) {
                float4 v2 = *(const float4*)(myout + 4 * k2);
                *(float4*)(od + 4 * k2) = v2;
            }
            asm volatile("" ::: "memory");
        }
    };

    int u = sb;
    stageA(u);
    reduceWrite();
    __syncthreads();                 // rp(u) ready
    for (;;) {
        int un = u + nsb;
        bool hn = un < NU;
        if (hn) stageA(un);          // loads fly under emit below
        emit(u);
        __syncthreads();             // all waves done reading rp(u)
        if (!hn) break;
        reduceWrite();               // regs -> rp(un)
        __syncthreads();             // rp(un) ready
        u = un;
    }
}

__global__ __launch_bounds__(256) void spp_fused(const float* __restrict__ feat,
                                                 float* __restrict__ out) {
    __shared__ float rp[CH * POOL * RPS];        // 11.2 KB
    __shared__ __align__(16) float owb[4 * 392]; // 6.3 KB
    int b = blockIdx.x;
    // Heavy-first segments; blocks per scale proportional to ny^2 (output
    // bytes), total 1024. Output patch offsets in scale order.
    if (b < 105)      run_segment<16>(b,       105, feat, out + (size_t)2539 * PE, rp, owb);
    else if (b < 222) run_segment<14>(b - 105, 117, feat, out + (size_t)2215 * PE, rp, owb);
    else if (b < 353) run_segment<12>(b - 222, 131, feat, out + (size_t)1854 * PE, rp, owb);
    else if (b < 498) run_segment<10>(b - 353, 145, feat, out + (size_t)1454 * PE, rp, owb);
    else if (b < 658) run_segment<8>(b - 498,  160, feat, out + (size_t)1013 * PE, rp, owb);
    else if (b < 833) run_segment<6>(b - 658,  175, feat, out + (size_t)529  * PE, rp, owb);
    else              run_segment<4>(b - 833,  191, feat, out,                     rp, owb);
}

extern "C" void kernel_launch(void* const* d_in, const int* in_sizes, int n_in,
                              void* d_out, int out_size, void* d_ws, size_t ws_size,
                              hipStream_t stream) {
    const float* feat = (const float*)d_in[0];
    float* out = (float*)d_out;
    spp_fused<<<1024, 256, 0, stream>>>(feat, out);
}